// Round 13
// baseline (1171.681 us; speedup 1.0000x reference)
//
#include <hip/hip_runtime.h>
#include <math.h>

#define NB 8
#define NN 4096
#define DD 256
#define CC 1024
#define NQ 8
#define ROWS (NB*NN)        // 32768
// fp16 1-pass: score = cn2 - 2*hi_a·hi_e, K=256.
// Dropped terms (hi_a·lo_e + lo_a·e): pair-difference score err std ~9e-3.
// TAU = 0.0625 ~ 7 sigma; flagged rows get exact fp32 re-argmin.
#define TAU 0.0625f

typedef unsigned short u16;
typedef __attribute__((ext_vector_type(8))) _Float16 f16x8;  // 8 f16 (4 VGPRs)
typedef __attribute__((ext_vector_type(4))) float f32x4;

// ---- exact RNE fp32->fp16 helpers (v_cvt_f16_f32 is RNE) ----
__device__ __forceinline__ u16 f2h(float f) {
  _Float16 h = (_Float16)f;
  return __builtin_bit_cast(u16, h);
}
__device__ __forceinline__ void hi4h(float4 f, ushort4& h) {
  h.x = f2h(f.x); h.y = f2h(f.y); h.z = f2h(f.z); h.w = f2h(f.w);
}

// merge candidate pair (w1,d1)<=(w2,d2) into running sorted top-2
__device__ __forceinline__ void merge_top2(float& v1, float& c1, float& v2, float& c2,
                                           float w1, float d1, float w2, float d2) {
  if (w1 < v1 || (w1 == v1 && d1 < c1)) {
    float nv2, nc2;
    if (v1 < w2 || (v1 == w2 && c1 < d2)) { nv2 = v1; nc2 = c1; }
    else                                  { nv2 = w2; nc2 = d2; }
    v1 = w1; c1 = d1; v2 = nv2; c2 = nc2;
  } else {
    if (w1 < v2 || (w1 == v2 && d1 < c2)) { v2 = w1; c2 = d1; }
  }
}

// ---------------------------------------------------------------------------
// x -> rsplit [ROWS][256] fp16 (hi only) ; also zero cnt (every launch!)
// ---------------------------------------------------------------------------
__global__ __launch_bounds__(256) void rvq_split0(
    const float* __restrict__ x, u16* __restrict__ rsplit, int* __restrict__ cnt)
{
  if (blockIdx.x == 0 && threadIdx.x < NQ) cnt[threadIdx.x] = 0;
  const size_t f = (size_t)blockIdx.x * 256 + threadIdx.x;   // float4 id (2M)
  const size_t row = f >> 6;
  const int c4 = (int)(f & 63) << 2;
  float4 v = ((const float4*)x)[f];
  ushort4 h; hi4h(v, h);
  *(ushort4*)(rsplit + row * 256 + c4) = h;
}

// ---------------------------------------------------------------------------
// ALL levels' codebooks -> esp [NQ*CC][256] fp16 hi (once)
// ---------------------------------------------------------------------------
__global__ __launch_bounds__(256) void rvq_esplit_all(
    const float* __restrict__ cb, u16* __restrict__ esp)
{
  const int f = blockIdx.x * 256 + threadIdx.x;              // float4 id (512K)
  const int row = f >> 6;                                    // global code 0..8191
  const int c4 = (f & 63) << 2;
  float4 v = ((const float4*)cb)[f];
  ushort4 h; hi4h(v, h);
  *(ushort4*)(esp + (size_t)row * 256 + c4) = h;
}

// ---------------------------------------------------------------------------
// ||e_c||^2 for all levels (fp32), one wave per code
// ---------------------------------------------------------------------------
__global__ __launch_bounds__(256) void rvq_norms(
    const float* __restrict__ cb, float* __restrict__ cn2)
{
  const int tid = threadIdx.x;
  const size_t code = (size_t)blockIdx.x * 4 + (tid >> 6);
  const int l = tid & 63;
  const float4 v = *reinterpret_cast<const float4*>(cb + code * DD + l * 4);
  float s = v.x * v.x + v.y * v.y + v.z * v.z + v.w * v.w;
  #pragma unroll
  for (int mm = 1; mm < 64; mm <<= 1) s += __shfl_xor(s, mm);
  if (l == 0) cn2[code] = s;
}

// ---------------------------------------------------------------------------
// BARRIER-FREE register-direct MFMA GEMM + per-wave top2.
// Each wave independently owns a 64x64 output tile: fragments loaded straight
// from global (L2-hot) into VGPRs, 2-deep register double-buffer, K=256 as
// 8 fully-unrolled steps.  NO __syncthreads / s_barrier anywhere; latency is
// hidden by 12 free-running waves/CU.  Wave-private LDS arena for the
// epilogue (R9 v2 shape), lgkmcnt-ordered within the wave.
// Grid 2048 x 256: block = 1 row-tile (64 rows) x 4 col-tiles (64 cols/wave).
// XCD decode keeps one row-tile's 4 blocks (16 col-tiles) on one XCD.
// ---------------------------------------------------------------------------
__global__ __launch_bounds__(256) void rvq_gemm_reg(
    const u16* __restrict__ rsplit,   // [ROWS][256]  fp16 hi
    const u16* __restrict__ esp,      // [CC][256]    fp16 hi (level)
    const float* __restrict__ cn2q,   // [CC]         (level)
    float4* __restrict__ top2)        // [16][ROWS]
{
  __shared__ float4 arena[4][64 * 8];  // 32 KB; wave-private 8KB regions

  const int tid = threadIdx.x;
  const int lane = tid & 63;
  const int wv = tid >> 6;
  const int fr = lane & 15, fg = lane >> 4;
  // XCD-locality decode: bid = rtHi*32 + ctg*8 + (rt%8)
  const int bid = blockIdx.x;
  const int rt = ((bid >> 5) << 3) | (bid & 7);   // 0..511 row tile
  const int ct = (((bid >> 3) & 3) << 2) | wv;    // 0..15 col tile (per wave)
  const size_t row0 = (size_t)rt * 64;

  // fragment base addresses (u16 units): lane (fr,fg) reads 16B at
  // row*256 + t*32 + fg*8 ; a[m] offsets by m*16 rows, b[n] by n*16 codes.
  const u16* aB = rsplit + (row0 + fr) * 256 + fg * 8;
  const u16* bB = esp + ((size_t)(ct * 64 + fr)) * 256 + fg * 8;

  f32x4 acc[4][4];
  #pragma unroll
  for (int m = 0; m < 4; ++m)
    #pragma unroll
    for (int n = 0; n < 4; ++n) acc[m][n] = (f32x4){0.f, 0.f, 0.f, 0.f};

  f16x8 a0[4], b0[4], a1[4], b1[4];

#define LOADF(adst, bdst, t)                                                  \
  {                                                                           \
    _Pragma("unroll")                                                         \
    for (int m = 0; m < 4; ++m)                                               \
      adst[m] = *(const f16x8*)(aB + m * 4096 + (t) * 32);                    \
    _Pragma("unroll")                                                         \
    for (int n = 0; n < 4; ++n)                                               \
      bdst[n] = *(const f16x8*)(bB + n * 4096 + (t) * 32);                    \
  }
#define MFMAS(a_, b_)                                                         \
  {                                                                           \
    _Pragma("unroll")                                                         \
    for (int m = 0; m < 4; ++m)                                               \
      _Pragma("unroll")                                                       \
      for (int n = 0; n < 4; ++n)                                             \
        acc[m][n] = __builtin_amdgcn_mfma_f32_16x16x32_f16(a_[m], b_[n],      \
                                                           acc[m][n], 0, 0, 0); \
  }

  // 8 steps, explicit 2-deep register double-buffer, no barriers at all
  LOADF(a0, b0, 0);
  LOADF(a1, b1, 1);
  MFMAS(a0, b0);
  LOADF(a0, b0, 2);
  MFMAS(a1, b1);
  LOADF(a1, b1, 3);
  MFMAS(a0, b0);
  LOADF(a0, b0, 4);
  MFMAS(a1, b1);
  LOADF(a1, b1, 5);
  MFMAS(a0, b0);
  LOADF(a0, b0, 6);
  MFMAS(a1, b1);
  LOADF(a1, b1, 7);
  MFMAS(a0, b0);
  MFMAS(a1, b1);
#undef LOADF
#undef MFMAS

  // ---- wave-private epilogue (no cross-wave sync needed) ----
  float cnv[4];
  #pragma unroll
  for (int n = 0; n < 4; ++n) cnv[n] = cn2q[ct * 64 + n * 16 + fr];
  float4* my = arena[wv];

  #pragma unroll
  for (int m = 0; m < 4; ++m)
    #pragma unroll
    for (int r = 0; r < 4; ++r) {
      float v1 = __builtin_inff(), c1 = 1.0e9f, v2 = __builtin_inff(), c2 = 1.0e9f;
      #pragma unroll
      for (int n = 0; n < 4; ++n) {          // ascending col: < keeps first-min
        const float sv = fmaf(-2.f, acc[m][n][r], cnv[n]);
        const float cf = (float)(ct * 64 + n * 16 + fr);
        if (sv < v1) { v2 = v1; c2 = c1; v1 = sv; c1 = cf; }
        else if (sv < v2) { v2 = sv; c2 = cf; }
      }
      // one butterfly: merge partner fr^1 (disjoint cols, tie-safe)
      float w1 = __shfl_xor(v1, 1), d1 = __shfl_xor(c1, 1);
      float w2 = __shfl_xor(v2, 1), d2 = __shfl_xor(c2, 1);
      merge_top2(v1, c1, v2, c2, w1, d1, w2, d2);
      if ((fr & 1) == 0) {
        const int row64 = m * 16 + fg * 4 + r;
        my[row64 * 8 + ((fr >> 1) ^ (row64 & 7))] = make_float4(v1, c1, v2, c2);
      }
    }

  // wave-local DS ordering, then gather: lane = row
  asm volatile("s_waitcnt lgkmcnt(0)" ::: "memory");
  __builtin_amdgcn_sched_barrier(0);
  {
    const int row64 = lane;
    float4 g0 = my[row64 * 8 + (0 ^ (row64 & 7))];
    float v1 = g0.x, c1 = g0.y, v2 = g0.z, c2 = g0.w;
    #pragma unroll
    for (int s = 1; s < 8; ++s) {
      float4 g = my[row64 * 8 + (s ^ (row64 & 7))];
      merge_top2(v1, c1, v2, c2, g.x, g.y, g.z, g.w);
    }
    top2[(size_t)ct * ROWS + row0 + row64] = make_float4(v1, c1, v2, c2);
  }
}

// ---------------------------------------------------------------------------
// merge 16 per-coltile top2 partials per row -> index + flag list
// ---------------------------------------------------------------------------
__global__ __launch_bounds__(256) void rvq_reduce(
    const float4* __restrict__ top2, float* __restrict__ idx_out,
    int* __restrict__ list, int* __restrict__ cnt, int level)
{
  const int row = blockIdx.x * 256 + threadIdx.x;
  float4 f = top2[row];                          // ct = 0
  float v1 = f.x, c1 = f.y, v2 = f.z, c2 = f.w;
  #pragma unroll
  for (int i = 1; i < 16; ++i) {                 // ct ascending = col ascending
    float4 g = top2[(size_t)i * ROWS + row];
    merge_top2(v1, c1, v2, c2, g.x, g.y, g.z, g.w);
  }
  idx_out[(size_t)row * NQ + level] = c1;
  if (v2 - v1 <= TAU) {
    int q = atomicAdd(cnt + level, 1);
    list[q] = row;
  }
}

// ---------------------------------------------------------------------------
// exact fp32 re-argmin for flagged rows (full 1024-code scan)
// ---------------------------------------------------------------------------
__global__ __launch_bounds__(256) void rvq_cleanup(
    const float* __restrict__ src, const float* __restrict__ cbq,
    const float* __restrict__ cn2q, const int* __restrict__ list,
    const int* __restrict__ cnt, float* __restrict__ idx_out, int level)
{
  __shared__ __align__(16) float rsh[DD];
  __shared__ float wmin[4];
  __shared__ int wcol[4];
  const int tid = threadIdx.x;
  const int n = cnt[level];
  for (int it = blockIdx.x; it < n; it += gridDim.x) {
    const int row = list[it];
    __syncthreads();
    rsh[tid] = src[(size_t)row * DD + tid];
    __syncthreads();
    float bv = __builtin_inff(); int bc = 1 << 29;
    #pragma unroll
    for (int cc4 = 0; cc4 < 4; ++cc4) {
      const int c = cc4 * 256 + tid;
      const float4* ep = (const float4*)(cbq + (size_t)c * DD);
      float dot = 0.f;
      #pragma unroll 8
      for (int k4 = 0; k4 < 64; ++k4) {
        float4 e4 = ep[k4];
        float4 r4 = *(const float4*)&rsh[k4 * 4];
        dot = fmaf(r4.x, e4.x, dot);
        dot = fmaf(r4.y, e4.y, dot);
        dot = fmaf(r4.z, e4.z, dot);
        dot = fmaf(r4.w, e4.w, dot);
      }
      float s = fmaf(-2.f, dot, cn2q[c]);
      if (s < bv || (s == bv && c < bc)) { bv = s; bc = c; }
    }
    #pragma unroll
    for (int mk = 1; mk < 64; mk <<= 1) {
      float ov = __shfl_xor(bv, mk); int oc = __shfl_xor(bc, mk);
      if (ov < bv || (ov == bv && oc < bc)) { bv = ov; bc = oc; }
    }
    if ((tid & 63) == 0) { wmin[tid >> 6] = bv; wcol[tid >> 6] = bc; }
    __syncthreads();
    if (tid == 0) {
      float v = wmin[0]; int c = wcol[0];
      #pragma unroll
      for (int w = 1; w < 4; ++w)
        if (wmin[w] < v || (wmin[w] == v && wcol[w] < c)) { v = wmin[w]; c = wcol[w]; }
      idx_out[(size_t)row * NQ + level] = (float)c;
    }
  }
}

// ---------------------------------------------------------------------------
// residual update: rn = src - e[idx]; levels 0-6: write res + fp16 hi split;
// level 7: write quantized_out = x - rn. Loss partials per 4-row block.
// ---------------------------------------------------------------------------
__global__ __launch_bounds__(256) void rvq_update_split(
    const float* __restrict__ x, const float* __restrict__ src,
    float* __restrict__ res, const float* __restrict__ cbq,
    const float* __restrict__ idx_f, u16* __restrict__ rsplit,
    float* __restrict__ partials, int level)
{
  const int tid = threadIdx.x;
  const size_t row = (size_t)blockIdx.x * 4 + (tid >> 6);
  const int seg = (tid & 63) << 2;
  const int idx = (int)idx_f[row * NQ + level];
  const float4 e = *reinterpret_cast<const float4*>(cbq + (size_t)idx * DD + seg);
  const float4 r = *reinterpret_cast<const float4*>(src + row * DD + seg);
  float4 rn = make_float4(r.x - e.x, r.y - e.y, r.z - e.z, r.w - e.w);
  if (level < 7) {
    *reinterpret_cast<float4*>(res + row * DD + seg) = rn;
    ushort4 h; hi4h(rn, h);
    *(ushort4*)(rsplit + row * 256 + seg) = h;
  } else {
    const float4 xv = *reinterpret_cast<const float4*>(x + row * DD + seg);
    *reinterpret_cast<float4*>(res + row * DD + seg) =
        make_float4(xv.x - rn.x, xv.y - rn.y, xv.z - rn.z, xv.w - rn.w);
  }
  float p = rn.x * rn.x + rn.y * rn.y + rn.z * rn.z + rn.w * rn.w;
  #pragma unroll
  for (int mm = 1; mm < 64; mm <<= 1) p += __shfl_xor(p, mm);
  __shared__ float w4[4];
  if ((tid & 63) == 0) w4[tid >> 6] = p;
  __syncthreads();
  if (tid == 0) partials[blockIdx.x] = w4[0] + w4[1] + w4[2] + w4[3];
}

__global__ __launch_bounds__(256) void rvq_loss(
    const float* __restrict__ partials, float* __restrict__ loss_out, int level)
{
  const int b = blockIdx.x;
  const int tid = threadIdx.x;
  float s = 0.f;
  for (int i = tid; i < 1024; i += 256) s += partials[b * 1024 + i];
  #pragma unroll
  for (int mm = 1; mm < 64; mm <<= 1) s += __shfl_xor(s, mm);
  __shared__ float w4[4];
  if ((tid & 63) == 0) w4[tid >> 6] = s;
  __syncthreads();
  if (tid == 0)
    loss_out[b * NQ + level] = (w4[0] + w4[1] + w4[2] + w4[3]) * (1.0f / 1048576.0f);
}

extern "C" void kernel_launch(void* const* d_in, const int* in_sizes, int n_in,
                              void* d_out, int out_size, void* d_ws, size_t ws_size,
                              hipStream_t stream) {
  const float* x  = (const float*)d_in[0];  // [8,4096,256]
  const float* cb = (const float*)d_in[1];  // [8,1024,256]
  float* out = (float*)d_out;

  // d_out layout (floats): quantized [ROWS*DD] | indices [ROWS*NQ] | losses [NB*NQ]
  float* res      = out;                    // residual shares quantized region
  float* out_idx  = out + (size_t)ROWS * DD;
  float* out_loss = out_idx + (size_t)ROWS * NQ;

  // workspace (~30 MB)
  char* w = (char*)d_ws;
  u16* rsplit = (u16*)w;                         w += (size_t)ROWS * 256 * 2;      // 16 MB (fp16 hi)
  u16* esp = (u16*)w;                            w += (size_t)NQ * CC * 256 * 2;   // 4 MB (fp16 hi)
  float4* top2 = (float4*)w;                     w += (size_t)16 * ROWS * 16;      // 8 MB
  int* list = (int*)w;                           w += (size_t)NQ * ROWS * 4;       // 1 MB
  float* cn2 = (float*)w;                        w += (size_t)NQ * CC * 4;
  float* partials = (float*)w;                   w += (size_t)(ROWS / 4) * 4;
  int* cnt = (int*)w;                            w += 64;

  rvq_split0<<<8192, 256, 0, stream>>>(x, rsplit, cnt);
  rvq_esplit_all<<<2048, 256, 0, stream>>>(cb, esp);
  rvq_norms<<<2048, 256, 0, stream>>>(cb, cn2);

  for (int q = 0; q < NQ; ++q) {
    const float* srcres = q ? res : x;
    const size_t eo = (size_t)q * CC * DD;
    rvq_gemm_reg<<<2048, 256, 0, stream>>>(
        rsplit, esp + (size_t)q * CC * 256, cn2 + (size_t)q * CC, top2);
    rvq_reduce<<<128, 256, 0, stream>>>(top2, out_idx, list + (size_t)q * ROWS, cnt, q);
    rvq_cleanup<<<512, 256, 0, stream>>>(
        srcres, cb + eo, cn2 + (size_t)q * CC, list + (size_t)q * ROWS, cnt, out_idx, q);
    rvq_update_split<<<ROWS / 4, 256, 0, stream>>>(
        x, srcres, res, cb + eo, out_idx, rsplit, partials, q);
    rvq_loss<<<NB, 256, 0, stream>>>(partials, out_loss, q);
  }
}